// Round 1
// baseline (12622.906 us; speedup 1.0000x reference)
//
#include <hip/hip_runtime.h>

typedef __attribute__((ext_vector_type(4))) float f32x4;
typedef __attribute__((ext_vector_type(8))) short short8;
typedef __attribute__((ext_vector_type(8))) __bf16 bf16x8;

static __device__ __forceinline__ unsigned short f2bf(float f) {
  unsigned u = __builtin_bit_cast(unsigned, f);
  u += 0x7FFFu + ((u >> 16) & 1u);
  return (unsigned short)(u >> 16);
}
static __device__ __forceinline__ float bf2f(unsigned short s) {
  unsigned u = ((unsigned)s) << 16;
  return __builtin_bit_cast(float, u);
}

// ---------------- prep kernels ----------------
__global__ void conv_k(const float* __restrict__ in, unsigned short* __restrict__ out, int n) {
  int i = blockIdx.x * 256 + threadIdx.x;
  if (i < n) out[i] = f2bf(in[i]);
}

// out[c*R + r] = bf16(in[r*C + c])   (transpose + convert)
__global__ void tconv_k(const float* __restrict__ in, unsigned short* __restrict__ out, int R, int C) {
  int i = blockIdx.x * 256 + threadIdx.x;
  if (i < R * C) {
    int r = i / C, c = i % C;
    out[c * R + r] = f2bf(in[i]);
  }
}

__global__ void zero_k(int* __restrict__ p, int n) {
  int i = blockIdx.x * 256 + threadIdx.x;
  if (i < n) p[i] = 0;
}

// bias_comb[o] = bd[o] + sum_h bo_f[h]*Wd[h][o] + bo_b[h]*Wd[512+h][o]
__global__ void bias_comb_k(const float* __restrict__ bo_f, const float* __restrict__ bo_b,
                            const float* __restrict__ Wd, const float* __restrict__ bd,
                            float* __restrict__ out) {
  int o = blockIdx.x * 256 + threadIdx.x;  // 512 total
  float s = bd[o];
  for (int h = 0; h < 512; ++h)
    s = fmaf(bo_f[h], Wd[h * 512 + o], fmaf(bo_b[h], Wd[(512 + h) * 512 + o], s));
  out[o] = s;
}

// ---------------- GEMM: C[M,N] = A[M,K] @ Bt[N,K]^T (+bias) ----------------
// 128x128 tile, BK=32, 256 threads, 4 waves in 2x2, each wave 64x64.
template <bool A_F32, bool PERM_A, bool DUAL, bool OUT_BF16, bool PERM_C, bool HAS_BIAS>
__global__ __launch_bounds__(256) void gemm_k(
    const void* __restrict__ Av, const unsigned short* __restrict__ Bt,
    const void* __restrict__ A2v, const unsigned short* __restrict__ Bt2,
    const float* __restrict__ bias, void* __restrict__ Cv, int M, int N, int K) {
  __shared__ __align__(16) unsigned short As[128][40];
  __shared__ __align__(16) unsigned short Bs[128][40];
  const int t = threadIdx.x;
  const int lane = t & 63, wid = t >> 6;
  const int wm = (wid >> 1) * 64, wn = (wid & 1) * 64;
  const int m0 = blockIdx.x * 128, n0 = blockIdx.y * 128;
  const int rif = lane & 15;        // row within 16-frag
  const int koff = (lane >> 4) * 8; // k element offset within 32
  f32x4 acc[4][4] = {};

  for (int pass = 0; pass < (DUAL ? 2 : 1); ++pass) {
    const void* A = pass ? A2v : Av;
    const unsigned short* B = pass ? Bt2 : Bt;
    for (int kt = 0; kt < K; kt += 32) {
      __syncthreads();
#pragma unroll
      for (int i = 0; i < 2; ++i) {
        int cid = t + i * 256;
        int tr = cid >> 2, kc = cid & 3;
        int gr = m0 + tr;
        long arow = PERM_A ? (long)(gr & 15) * 2048 + (gr >> 4) : (long)gr;
        if constexpr (A_F32) {
          const float* ap = (const float*)A + arow * K + kt + kc * 8;
          float4 x0 = *(const float4*)ap;
          float4 x1 = *(const float4*)(ap + 4);
          unsigned short* d = &As[tr][kc * 8];
          d[0] = f2bf(x0.x); d[1] = f2bf(x0.y); d[2] = f2bf(x0.z); d[3] = f2bf(x0.w);
          d[4] = f2bf(x1.x); d[5] = f2bf(x1.y); d[6] = f2bf(x1.z); d[7] = f2bf(x1.w);
        } else {
          uint4 v = *(const uint4*)((const unsigned short*)A + arow * K + kt + kc * 8);
          *(uint4*)&As[tr][kc * 8] = v;
        }
        uint4 bv = *(const uint4*)(B + (long)(n0 + tr) * K + kt + kc * 8);
        *(uint4*)&Bs[tr][kc * 8] = bv;
      }
      __syncthreads();
      short8 af[4], bf[4];
#pragma unroll
      for (int mt = 0; mt < 4; ++mt) af[mt] = *(const short8*)&As[wm + mt * 16 + rif][koff];
#pragma unroll
      for (int nt = 0; nt < 4; ++nt) bf[nt] = *(const short8*)&Bs[wn + nt * 16 + rif][koff];
#pragma unroll
      for (int mt = 0; mt < 4; ++mt)
#pragma unroll
        for (int nt = 0; nt < 4; ++nt)
          acc[mt][nt] = __builtin_amdgcn_mfma_f32_16x16x32_bf16(
              __builtin_bit_cast(bf16x8, af[mt]), __builtin_bit_cast(bf16x8, bf[nt]),
              acc[mt][nt], 0, 0, 0);
    }
  }

  const int cr = (lane >> 4) * 4;
#pragma unroll
  for (int mt = 0; mt < 4; ++mt)
#pragma unroll
    for (int nt = 0; nt < 4; ++nt)
#pragma unroll
      for (int r = 0; r < 4; ++r) {
        int row = m0 + wm + mt * 16 + cr + r;
        int col = n0 + wn + nt * 16 + rif;
        float v = acc[mt][nt][r];
        if constexpr (HAS_BIAS) v += bias[col];
        if constexpr (OUT_BF16) {
          ((unsigned short*)Cv)[(long)row * N + col] = f2bf(v);
        } else {
          long orow = PERM_C ? (long)(row & 15) * 2048 + (row >> 4) : (long)row;
          ((float*)Cv)[orow * N + col] = v;
        }
      }
}

// ---------------- sequential scan ----------------
// grid = 8 blocks x 256 threads. block b: dir=b>>2, slot=b&3.
// Each wave owns 32 output columns; Wh^T slice lives in registers.
// hs buffer initially holds pre (input projection); overwritten in place with h.
__global__ __launch_bounds__(256, 1) void scan_k(
    unsigned short* __restrict__ hs_f, unsigned short* __restrict__ hs_b,
    const unsigned short* __restrict__ WhT_f, const unsigned short* __restrict__ WhT_b,
    int* __restrict__ cnt /* [2][2048] */) {
  const int dir = blockIdx.x >> 2;
  const int slot = blockIdx.x & 3;
  const int lane = threadIdx.x & 63;
  const int wid = threadIdx.x >> 6;
  const int colbase = slot * 128 + wid * 32;
  const int r0 = lane & 15;
  const int g8 = (lane >> 4) * 8;
  const int cr = (lane >> 4) * 4;
  unsigned short* hs = dir ? hs_b : hs_f;
  const unsigned short* WhT = dir ? WhT_b : WhT_f;
  int* myc = cnt + dir * 2048;

  // Wh^T fragments: B[k][n] with n = colbase + nn*16 + (lane&15), k = c*32 + (lane>>4)*8 + j
  short8 Bf[2][16];
#pragma unroll
  for (int n = 0; n < 2; ++n)
#pragma unroll
    for (int c = 0; c < 16; ++c)
      Bf[n][c] = *(const short8*)(WhT + (unsigned)(colbase + n * 16 + r0) * 512 + c * 32 + g8);

#pragma unroll 1
  for (int t = 0; t < 2048; ++t) {
    const int l = dir ? (2047 - t) : t;
    // pre values for this step (buffer row l still holds pre) - normal cached loads
    float pr[2][4];
#pragma unroll
    for (int n = 0; n < 2; ++n)
#pragma unroll
      for (int r = 0; r < 4; ++r)
        pr[n][r] = bf2f(hs[(unsigned)(l * 16 + cr + r) * 512 + colbase + n * 16 + r0]);

    f32x4 acc[2];
#pragma unroll
    for (int n = 0; n < 2; ++n) {
      acc[n][0] = pr[n][0]; acc[n][1] = pr[n][1];
      acc[n][2] = pr[n][2]; acc[n][3] = pr[n][3];
    }

    if (t > 0) {
      // wait for all 16 waves of this direction to finish step t-1
      while (__hip_atomic_load(myc + (t - 1), __ATOMIC_RELAXED, __HIP_MEMORY_SCOPE_AGENT) != 16) {}
      __builtin_amdgcn_fence(__ATOMIC_ACQUIRE, "agent");
      const int lp = dir ? (l + 1) : (l - 1);
      short8 Af[16];
#pragma unroll
      for (int c = 0; c < 16; ++c) {
        const unsigned long long* p =
            (const unsigned long long*)(hs + (unsigned)(lp * 16 + r0) * 512 + c * 32 + g8);
        unsigned long long lo = __hip_atomic_load(p, __ATOMIC_RELAXED, __HIP_MEMORY_SCOPE_AGENT);
        unsigned long long hi = __hip_atomic_load(p + 1, __ATOMIC_RELAXED, __HIP_MEMORY_SCOPE_AGENT);
        union { unsigned long long q[2]; short8 s; } u;
        u.q[0] = lo; u.q[1] = hi;
        Af[c] = u.s;
      }
#pragma unroll
      for (int c = 0; c < 16; ++c)
#pragma unroll
        for (int n = 0; n < 2; ++n)
          acc[n] = __builtin_amdgcn_mfma_f32_16x16x32_bf16(
              __builtin_bit_cast(bf16x8, Af[c]), __builtin_bit_cast(bf16x8, Bf[n][c]),
              acc[n], 0, 0, 0);
    }

    // h = tanh(acc), write in place (normal stores; release fence makes them agent-visible)
#pragma unroll
    for (int n = 0; n < 2; ++n)
#pragma unroll
      for (int r = 0; r < 4; ++r) {
        float x = acc[n][r];
        x = fminf(fmaxf(x, -9.f), 9.f);
        float e = __expf(2.f * x);
        float h = __fdividef(e - 1.f, e + 1.f);
        hs[(unsigned)(l * 16 + cr + r) * 512 + colbase + n * 16 + r0] = f2bf(h);
      }
    __builtin_amdgcn_fence(__ATOMIC_RELEASE, "agent");
    if (lane == 0)
      __hip_atomic_fetch_add(myc + t, 1, __ATOMIC_RELAXED, __HIP_MEMORY_SCOPE_AGENT);
  }
}

// ---------------- host ----------------
extern "C" void kernel_launch(void* const* d_in, const int* in_sizes, int n_in,
                              void* d_out, int out_size, void* d_ws, size_t ws_size,
                              hipStream_t stream) {
  (void)in_sizes; (void)n_in; (void)out_size; (void)ws_size;
  const float* x    = (const float*)d_in[0];
  // d_in[1] = c (unused by reference)
  const float* Wx_f = (const float*)d_in[2];
  const float* Wh_f = (const float*)d_in[3];
  const float* b_f  = (const float*)d_in[4];
  const float* Wo_f = (const float*)d_in[5];
  const float* bo_f = (const float*)d_in[6];
  const float* Wx_b = (const float*)d_in[7];
  const float* Wh_b = (const float*)d_in[8];
  const float* b_b  = (const float*)d_in[9];
  const float* Wo_b = (const float*)d_in[10];
  const float* bo_b = (const float*)d_in[11];
  const float* Wd   = (const float*)d_in[12];
  const float* bd   = (const float*)d_in[13];

  char* ws = (char*)d_ws;
  size_t off = 0;
  auto alloc = [&](size_t bytes) {
    char* p = ws + off;
    off = (off + bytes + 255) & ~(size_t)255;
    return p;
  };
  const size_t PRE_BYTES = (size_t)2048 * 16 * 512 * 2;  // [L][16][512] bf16
  const size_t WB = (size_t)512 * 512 * 2;
  unsigned short* pre_f = (unsigned short*)alloc(PRE_BYTES);  // becomes hs_f
  unsigned short* pre_b = (unsigned short*)alloc(PRE_BYTES);  // becomes hs_b
  unsigned short* wxT_f = (unsigned short*)alloc(WB);
  unsigned short* wxT_b = (unsigned short*)alloc(WB);
  unsigned short* whT_f = (unsigned short*)alloc(WB);
  unsigned short* whT_b = (unsigned short*)alloc(WB);
  unsigned short* wdT_t = (unsigned short*)alloc(WB);
  unsigned short* wdT_b = (unsigned short*)alloc(WB);
  unsigned short* wo_fb = (unsigned short*)alloc(WB);
  unsigned short* wo_bb = (unsigned short*)alloc(WB);
  unsigned short* wcT_f = (unsigned short*)alloc(WB);
  unsigned short* wcT_b = (unsigned short*)alloc(WB);
  int* cnt = (int*)alloc((size_t)2 * 2048 * 4);
  float* bias_c = (float*)alloc(512 * 4);

  // weight prep
  tconv_k<<<1024, 256, 0, stream>>>(Wx_f, wxT_f, 512, 512);
  tconv_k<<<1024, 256, 0, stream>>>(Wx_b, wxT_b, 512, 512);
  tconv_k<<<1024, 256, 0, stream>>>(Wh_f, whT_f, 512, 512);
  tconv_k<<<1024, 256, 0, stream>>>(Wh_b, whT_b, 512, 512);
  tconv_k<<<1024, 256, 0, stream>>>(Wd, wdT_t, 512, 512);
  tconv_k<<<1024, 256, 0, stream>>>(Wd + 512 * 512, wdT_b, 512, 512);
  conv_k<<<1024, 256, 0, stream>>>(Wo_f, wo_fb, 512 * 512);
  conv_k<<<1024, 256, 0, stream>>>(Wo_b, wo_bb, 512 * 512);
  zero_k<<<16, 256, 0, stream>>>(cnt, 2 * 2048);

  // fold: WcombT = WdT_half @ Wo^T  (C row-major [o][h] == Bt for phase 3)
  gemm_k<false, false, false, true, false, false><<<dim3(4, 4), 256, 0, stream>>>(
      wdT_t, wo_fb, nullptr, nullptr, nullptr, wcT_f, 512, 512, 512);
  gemm_k<false, false, false, true, false, false><<<dim3(4, 4), 256, 0, stream>>>(
      wdT_b, wo_bb, nullptr, nullptr, nullptr, wcT_b, 512, 512, 512);
  bias_comb_k<<<2, 256, 0, stream>>>(bo_f, bo_b, Wd, bd, bias_c);

  // phase 1: pre[l*16+b][h] = x[b][l][:] @ Wx + b   (A f32 with row permute)
  gemm_k<true, true, false, true, false, true><<<dim3(256, 4), 256, 0, stream>>>(
      x, wxT_f, nullptr, nullptr, b_f, pre_f, 32768, 512, 512);
  gemm_k<true, true, false, true, false, true><<<dim3(256, 4), 256, 0, stream>>>(
      x, wxT_b, nullptr, nullptr, b_b, pre_b, 32768, 512, 512);

  // phase 2: sequential scan (both directions concurrently)
  scan_k<<<8, 256, 0, stream>>>(pre_f, pre_b, whT_f, whT_b, cnt);

  // phase 3: out[b][l][o] = hs_f @ WcombT_f^T + hs_b @ WcombT_b^T + bias_comb
  gemm_k<false, false, true, false, true, true><<<dim3(256, 4), 256, 0, stream>>>(
      pre_f, wcT_f, pre_b, wcT_b, bias_c, d_out, 32768, 512, 512);
}